// Round 1
// baseline (20207.001 us; speedup 1.0000x reference)
//
#include <hip/hip_runtime.h>
#include <math.h>

// ---------------------------------------------------------------------------
// Long-short transformer encoder (L=4,B=8,N=2048,D=512,H=8,DH=64,W=128,S=16,
// R=1,DFF=2048,K1=9,K2=1), full fp32, MI355X.
// Structure per layer:
//   LN -> Q/KV GEMM -> rope -> headwise LN(KV) -> global-KV summar. -> fused
//   local+global attention -> Wo GEMM (+bias+resid+maskzero) -> LN ->
//   conv1 (9-shift GEMM, bias+GELU) -> conv2 GEMM (+bias+resid+maskzero)
// ---------------------------------------------------------------------------

#define NEGF (-3.4028234663852886e38f)

#define SEQ    2048
#define DMODEL 512
#define NROWS  16384   // B*N

// ---------------------------- mask normalization ---------------------------
// jnp bool mask may arrive as bool(1B)/int32/int64/float32. Detect byte layout
// on-device and normalize to int32 0/1 (1 = True = keep-key / zero-out-x).
__global__ __launch_bounds__(256) void mask_detect_kernel(
    const unsigned char* __restrict__ m, int* __restrict__ flags)
{
    __shared__ int sA, sB;
    const int tid = threadIdx.x;
    if (tid == 0) { sA = 0; sB = 0; }
    __syncthreads();
    int a = 0, b8 = 0;
    for (int i = tid; i < 16384; i += 256) {
        const unsigned char v = m[i];
        if (i & 3) a |= v;
        if ((i & 7) == 4) b8 |= v;
    }
    atomicOr(&sA, a);
    atomicOr(&sB, b8);
    __syncthreads();
    if (tid == 0) { flags[0] = sA; flags[1] = sB; }
}

__global__ __launch_bounds__(256) void mask_norm_kernel(
    const unsigned char* __restrict__ m, const int* __restrict__ flags,
    int* __restrict__ out)
{
    const int i = blockIdx.x * 256 + threadIdx.x;  // < 16384
    const int a = flags[0], b8 = flags[1];
    int v;
    if (a == 0)               v = b8 ? m[4L * i] : m[8L * i];   // int32 / int64
    else if ((a & ~1) == 0)   v = m[i];                         // bool bytes
    else                      v = (m[4L*i+1] | m[4L*i+2] | m[4L*i+3]) != 0; // f32
    out[i] = (v != 0) ? 1 : 0;
}

// --------------------------- embedding + sinusoid --------------------------
__global__ __launch_bounds__(256) void embed_kernel(
    const int* __restrict__ seq, const float* __restrict__ emb,
    float* __restrict__ X, float* __restrict__ we)
{
    const long idx = (long)blockIdx.x * 256 + threadIdx.x;  // < 8388608
    const int  d  = (int)(idx & 511);
    const long bn = idx >> 9;
    const int  n  = (int)(bn & (SEQ - 1));
    const int tok = seq[bn];
    const float e = emb[(long)tok * DMODEL + d];
    we[idx] = e;
    const float denom = (float)pow(10000.0, (double)(d & ~1) / 512.0);
    const float angle = (float)n / denom;
    const float sval  = (d & 1) ? cosf(angle) : sinf(angle);
    X[idx] = e + sval;
}

// ------------------------------- row LayerNorm -----------------------------
__global__ __launch_bounds__(256) void ln_row_kernel(
    const float* __restrict__ X, float* __restrict__ Y,
    const float* __restrict__ g, const float* __restrict__ bb)
{
    const int row = blockIdx.x;
    const int tid = threadIdx.x;
    const float2 v = *(const float2*)&X[(long)row * DMODEL + tid * 2];
    float s  = v.x + v.y;
    float sq = v.x * v.x + v.y * v.y;
    #pragma unroll
    for (int o = 32; o > 0; o >>= 1) { s += __shfl_xor(s, o); sq += __shfl_xor(sq, o); }
    __shared__ float rs[4], rq[4];
    const int wv = tid >> 6, lane = tid & 63;
    if (lane == 0) { rs[wv] = s; rq[wv] = sq; }
    __syncthreads();
    s  = rs[0] + rs[1] + rs[2] + rs[3];
    sq = rq[0] + rq[1] + rq[2] + rq[3];
    const float mean = s * (1.f / 512.f);
    const float var  = sq * (1.f / 512.f) - mean * mean;
    const float inv  = rsqrtf(var + 1e-5f);
    const float2 gv = *(const float2*)&g[tid * 2];
    const float2 bv = *(const float2*)&bb[tid * 2];
    float2 o;
    o.x = (v.x - mean) * inv * gv.x + bv.x;
    o.y = (v.y - mean) * inv * gv.y + bv.y;
    *(float2*)&Y[(long)row * DMODEL + tid * 2] = o;
}

// ------------------------- head-wise LayerNorm (DH=64) ---------------------
__global__ __launch_bounds__(256) void ln_head_kernel(
    const float* __restrict__ X, float* __restrict__ Y,
    const float* __restrict__ g, const float* __restrict__ bb)
{
    const int grp  = blockIdx.x * 4 + (threadIdx.x >> 6);  // (b*N+n)*8+h
    const int lane = threadIdx.x & 63;
    const long off = (long)grp * 64 + lane;
    const float x = X[off];
    float mean = x;
    #pragma unroll
    for (int o = 32; o > 0; o >>= 1) mean += __shfl_xor(mean, o);
    mean *= (1.f / 64.f);
    const float d = x - mean;
    float var = d * d;
    #pragma unroll
    for (int o = 32; o > 0; o >>= 1) var += __shfl_xor(var, o);
    var *= (1.f / 64.f);
    Y[off] = d * rsqrtf(var + 1e-5f) * g[lane] + bb[lane];
}

// ---------------------------------- rotary ---------------------------------
__global__ __launch_bounds__(256) void rope_kernel(float* __restrict__ T, float scale)
{
    const long idx = (long)blockIdx.x * 256 + threadIdx.x;  // < 4194304
    const int  i   = (int)(idx & 31);
    const long rem = idx >> 5;
    const int  h   = (int)(rem & 7);
    const long bn  = rem >> 3;
    const int  n   = (int)(bn & (SEQ - 1));
    const float inv = (float)pow(10000.0, -(double)i / 32.0);
    const float f = (float)n * inv;
    float s, c;
    sincosf(f, &s, &c);
    const long o = bn * DMODEL + (long)h * 64 + i;
    const float t0 = T[o], t1 = T[o + 32];
    T[o]      = (t0 * c - t1 * s) * scale;
    T[o + 32] = (t1 * c + t0 * s) * scale;
}

// --------------------- global KV summaries (Wp, softmax, LN) ---------------
__global__ __launch_bounds__(256) void globalkv_kernel(
    const float* __restrict__ KV, const float* __restrict__ Wp,
    const float* __restrict__ gng, const float* __restrict__ gnb,
    const int* __restrict__ maskn, float* __restrict__ G)
{
    const int tid  = threadIdx.x;
    const int lane = tid & 63;
    const int wv   = tid >> 6;
    const int grp  = blockIdx.x * 4 + wv;     // bh*128 + s, < 8192
    const int bh   = grp >> 7;
    const int sseg = grp & 127;
    const int b = bh >> 3, h = bh & 7;
    const float wp = Wp[lane];
    const float* base = KV + ((long)(b * SEQ + sseg * 16)) * DMODEL + h * 64 + lane;
    float kvv[16], p[16];
    #pragma unroll
    for (int i = 0; i < 16; ++i) kvv[i] = base[(long)i * DMODEL];
    #pragma unroll
    for (int i = 0; i < 16; ++i) {
        float t = kvv[i] * wp;
        #pragma unroll
        for (int o = 32; o > 0; o >>= 1) t += __shfl_xor(t, o);
        const int keep = maskn[b * SEQ + sseg * 16 + i];
        p[i] = keep ? t : NEGF;
    }
    float m = p[0];
    #pragma unroll
    for (int i = 1; i < 16; ++i) m = fmaxf(m, p[i]);
    float sum = 0.f;
    #pragma unroll
    for (int i = 0; i < 16; ++i) { p[i] = expf(p[i] - m); sum += p[i]; }
    const float inv = 1.f / sum;     // all-masked segment -> uniform (JAX semantics)
    float gd = 0.f;
    #pragma unroll
    for (int i = 0; i < 16; ++i) gd = fmaf(p[i] * inv, kvv[i], gd);
    float mean = gd;
    #pragma unroll
    for (int o = 32; o > 0; o >>= 1) mean += __shfl_xor(mean, o);
    mean *= (1.f / 64.f);
    const float d = gd - mean;
    float var = d * d;
    #pragma unroll
    for (int o = 32; o > 0; o >>= 1) var += __shfl_xor(var, o);
    var *= (1.f / 64.f);
    G[(long)grp * 64 + lane] = d * rsqrtf(var + 1e-5f) * gng[lane] + gnb[lane];
}

// ----------------------- fused long-short attention ------------------------
// Block = (window w, bh). 384 key/value slots: 0..127 = global g, 128..383 =
// local lkv (windows w-1,w; LN'd). sim row masks: global causal, local pad /
// key-mask / causal. Exact softmax-with-max semantics (all-NEG -> uniform).
__global__ __launch_bounds__(256) void attn_kernel(
    const float* __restrict__ Q, const float* __restrict__ KVLN,
    const float* __restrict__ G, const float* __restrict__ lnb,
    const int* __restrict__ maskn, float* __restrict__ AO)
{
    __shared__ float sk[384][65];                  // keys == values
    __shared__ float qs[128][64];
    __shared__ __align__(16) float ps[4][384][4];  // per-wave probs (4 rows)
    __shared__ int lm[256];
    const int w  = blockIdx.x;   // 0..15
    const int bh = blockIdx.y;   // 0..63
    const int b = bh >> 3, h = bh & 7;
    const int tid = threadIdx.x;
    const int lane = tid & 63;
    const int wv = tid >> 6;

    for (int idx = tid; idx < 384 * 16; idx += 256) {
        const int slot = idx >> 4;
        const int dq = (idx & 15) << 2;
        float4 v;
        if (slot < 128) {
            v = *(const float4*)&G[((long)(bh * 128 + slot)) * 64 + dq];
        } else {
            const int kn = (w - 1) * 128 + (slot - 128);
            if (kn < 0) v = make_float4(lnb[dq], lnb[dq+1], lnb[dq+2], lnb[dq+3]); // LN(-1 vec)=lnb
            else v = *(const float4*)&KVLN[((long)(b * SEQ + kn)) * DMODEL + h * 64 + dq];
        }
        sk[slot][dq] = v.x; sk[slot][dq+1] = v.y; sk[slot][dq+2] = v.z; sk[slot][dq+3] = v.w;
    }
    for (int idx = tid; idx < 128 * 16; idx += 256) {
        const int r = idx >> 4;
        const int dq = (idx & 15) << 2;
        const float4 v = *(const float4*)&Q[((long)(b * SEQ + w * 128 + r)) * DMODEL + h * 64 + dq];
        qs[r][dq] = v.x; qs[r][dq+1] = v.y; qs[r][dq+2] = v.z; qs[r][dq+3] = v.w;
    }
    {
        const int kn = (w - 1) * 128 + tid;
        lm[tid & 255] = (kn >= 0 && tid < 256) ? maskn[b * SEQ + kn] : (tid < 256 ? 0 : lm[tid & 255]);
    }
    __syncthreads();

    for (int g4 = 0; g4 < 8; ++g4) {
        const int i0 = wv * 32 + g4 * 4;
        float s[4][6];
        #pragma unroll
        for (int r = 0; r < 4; ++r) {
            #pragma unroll
            for (int t = 0; t < 6; ++t) s[r][t] = 0.f;
        }
        #pragma unroll 4
        for (int k = 0; k < 64; ++k) {
            const float q0 = qs[i0 + 0][k];
            const float q1 = qs[i0 + 1][k];
            const float q2 = qs[i0 + 2][k];
            const float q3 = qs[i0 + 3][k];
            #pragma unroll
            for (int t = 0; t < 6; ++t) {
                const float kv = sk[t * 64 + lane][k];
                s[0][t] = fmaf(q0, kv, s[0][t]);
                s[1][t] = fmaf(q1, kv, s[1][t]);
                s[2][t] = fmaf(q2, kv, s[2][t]);
                s[3][t] = fmaf(q3, kv, s[3][t]);
            }
        }
        #pragma unroll
        for (int r = 0; r < 4; ++r) {
            const int i = i0 + r;
            const int n = w * 128 + i;
            #pragma unroll
            for (int t = 0; t < 6; ++t) {
                const int j = t * 64 + lane;
                bool ok;
                if (j < 128) ok = (n >= (j + 1) * 16 - 1);               // global causal
                else {
                    const int jj = j - 128;
                    ok = (jj <= i + 128) && (lm[jj] != 0);               // causal + key mask (+pad)
                }
                if (!ok) s[r][t] = NEGF;
            }
            float m = s[r][0];
            #pragma unroll
            for (int t = 1; t < 6; ++t) m = fmaxf(m, s[r][t]);
            #pragma unroll
            for (int o = 32; o > 0; o >>= 1) m = fmaxf(m, __shfl_xor(m, o));
            float e[6]; float sum = 0.f;
            #pragma unroll
            for (int t = 0; t < 6; ++t) { e[t] = expf(s[r][t] - m); sum += e[t]; }
            #pragma unroll
            for (int o = 32; o > 0; o >>= 1) sum += __shfl_xor(sum, o);
            const float inv = 1.f / sum;
            #pragma unroll
            for (int t = 0; t < 6; ++t) ps[wv][t * 64 + lane][r] = e[t] * inv;
        }
        __syncthreads();
        float o0 = 0.f, o1 = 0.f, o2 = 0.f, o3 = 0.f;
        #pragma unroll 4
        for (int j = 0; j < 384; ++j) {
            const float kv = sk[j][lane];
            const float4 p4 = *(const float4*)&ps[wv][j][0];
            o0 = fmaf(p4.x, kv, o0);
            o1 = fmaf(p4.y, kv, o1);
            o2 = fmaf(p4.z, kv, o2);
            o3 = fmaf(p4.w, kv, o3);
        }
        const long obase = ((long)(b * SEQ + w * 128 + i0)) * DMODEL + h * 64 + lane;
        AO[obase]              = o0;
        AO[obase + DMODEL]     = o1;
        AO[obase + 2 * DMODEL] = o2;
        AO[obase + 3 * DMODEL] = o3;
    }
}

// ----------------------- w1 [f][c][k] -> w1t [k][f][c] ---------------------
__global__ __launch_bounds__(256) void w1t_kernel(
    const float* __restrict__ w1, float* __restrict__ w1t)
{
    __shared__ float ld[4608];
    const int f = blockIdx.x;      // 0..2047
    const float* src = w1 + (long)f * 4608;
    for (int i = threadIdx.x; i < 4608; i += 256) ld[i] = src[i];
    __syncthreads();
    for (int k = 0; k < 9; ++k)
        for (int c = threadIdx.x; c < 512; c += 256)
            w1t[(long)k * 1048576 + (long)f * 512 + c] = ld[c * 9 + k];
}

// ------------------------------ generic GEMM-NT ----------------------------
// C[r][c] = sum_sh sum_k A[r + ashift0+sh][k] * B_sh[c][k]   (B_sh = B + sh*bshift)
// Rows shifted within their 2048-long sequence; out-of-range -> zero (conv pad).
// Epilogue: +bias, GELU(exact), +resid, mask-zero.
__global__ __launch_bounds__(256) void gemm_nt_kernel(
    const float* __restrict__ A, int lda,
    const float* __restrict__ B, int ldb, long bshift, int nshift, int ashift0,
    float* __restrict__ C, int ldc, int K,
    const float* __restrict__ bias, const float* __restrict__ resid,
    const int* __restrict__ maskrow, int gelu_flag)
{
    constexpr int BK = 16;
    __shared__ __align__(16) float As[BK][132];
    __shared__ __align__(16) float Bs[BK][132];
    const int tid  = threadIdx.x;
    const int row0 = blockIdx.x * 128;
    const int col0 = blockIdx.y * 128;
    const int lr = tid >> 1;
    const int lk = (tid & 1) * 8;
    const int ty = tid >> 4;
    const int tx = tid & 15;
    const int ar = row0 + lr;
    const int an = ar & (SEQ - 1);
    const int bc = col0 + lr;

    float acc[8][8];
    #pragma unroll
    for (int i = 0; i < 8; ++i) {
        #pragma unroll
        for (int j = 0; j < 8; ++j) acc[i][j] = 0.f;
    }

    for (int sh = 0; sh < nshift; ++sh) {
        const int ashift = ashift0 + sh;
        const int nn = an + ashift;
        const bool aval = (nn >= 0) && (nn < SEQ);
        const float* Ap = A + (long)(ar + ashift) * lda + lk;
        const float* Bp = B + (long)sh * bshift + (long)bc * ldb + lk;
        for (int k0 = 0; k0 < K; k0 += BK) {
            float4 a0, a1, b0, b1;
            if (aval) {
                a0 = *(const float4*)(Ap + k0);
                a1 = *(const float4*)(Ap + k0 + 4);
            } else {
                a0 = make_float4(0.f, 0.f, 0.f, 0.f); a1 = a0;
            }
            b0 = *(const float4*)(Bp + k0);
            b1 = *(const float4*)(Bp + k0 + 4);
            __syncthreads();
            As[lk+0][lr]=a0.x; As[lk+1][lr]=a0.y; As[lk+2][lr]=a0.z; As[lk+3][lr]=a0.w;
            As[lk+4][lr]=a1.x; As[lk+5][lr]=a1.y; As[lk+6][lr]=a1.z; As[lk+7][lr]=a1.w;
            Bs[lk+0][lr]=b0.x; Bs[lk+1][lr]=b0.y; Bs[lk+2][lr]=b0.z; Bs[lk+3][lr]=b0.w;
            Bs[lk+4][lr]=b1.x; Bs[lk+5][lr]=b1.y; Bs[lk+6][lr]=b1.z; Bs[lk+7][lr]=b1.w;
            __syncthreads();
            #pragma unroll
            for (int k = 0; k < BK; ++k) {
                float a[8], b[8];
                *(float4*)(a)     = *(const float4*)&As[k][ty * 8];
                *(float4*)(a + 4) = *(const float4*)&As[k][ty * 8 + 4];
                *(float4*)(b)     = *(const float4*)&Bs[k][tx * 8];
                *(float4*)(b + 4) = *(const float4*)&Bs[k][tx * 8 + 4];
                #pragma unroll
                for (int i = 0; i < 8; ++i) {
                    #pragma unroll
                    for (int j = 0; j < 8; ++j)
                        acc[i][j] = fmaf(a[i], b[j], acc[i][j]);
                }
            }
        }
    }
    #pragma unroll
    for (int i = 0; i < 8; ++i) {
        const int r = row0 + ty * 8 + i;
        const int mz = maskrow ? maskrow[r] : 0;
        float* Crow = C + (long)r * ldc;
        const float* Rrow = resid ? resid + (long)r * ldc : nullptr;
        #pragma unroll
        for (int jv = 0; jv < 8; jv += 4) {
            const int c = col0 + tx * 8 + jv;
            float v[4] = {acc[i][jv], acc[i][jv+1], acc[i][jv+2], acc[i][jv+3]};
            if (bias) {
                const float4 bv = *(const float4*)&bias[c];
                v[0] += bv.x; v[1] += bv.y; v[2] += bv.z; v[3] += bv.w;
            }
            if (gelu_flag) {
                #pragma unroll
                for (int q = 0; q < 4; ++q)
                    v[q] = 0.5f * v[q] * (1.f + erff(v[q] * 0.70710678118654752f));
            }
            if (Rrow) {
                const float4 rv = *(const float4*)&Rrow[c];
                v[0] += rv.x; v[1] += rv.y; v[2] += rv.z; v[3] += rv.w;
            }
            if (mz) { v[0] = v[1] = v[2] = v[3] = 0.f; }
            *(float4*)&Crow[c] = make_float4(v[0], v[1], v[2], v[3]);
        }
    }
}

// --------------------------------- launcher --------------------------------
extern "C" void kernel_launch(void* const* d_in, const int* in_sizes, int n_in,
                              void* d_out, int out_size, void* d_ws, size_t ws_size,
                              hipStream_t stream)
{
    (void)in_sizes; (void)n_in; (void)out_size; (void)ws_size;
    const int*   src_seq = (const int*)d_in[0];
    const void*  mraw    = d_in[1];
    const float* emb     = (const float*)d_in[2];
    const float* ln1_g   = (const float*)d_in[3];
    const float* ln1_b   = (const float*)d_in[4];
    const float* Wq      = (const float*)d_in[5];
    const float* Wkv     = (const float*)d_in[6];
    const float* Wp      = (const float*)d_in[7];
    const float* lng     = (const float*)d_in[8];
    const float* lnb     = (const float*)d_in[9];
    const float* gng     = (const float*)d_in[10];
    const float* gnb     = (const float*)d_in[11];
    const float* Wo      = (const float*)d_in[12];
    const float* bo      = (const float*)d_in[13];
    const float* ln2_g   = (const float*)d_in[14];
    const float* ln2_b   = (const float*)d_in[15];
    const float* w1      = (const float*)d_in[16];
    const float* b1      = (const float*)d_in[17];
    const float* w2      = (const float*)d_in[18];
    const float* b2      = (const float*)d_in[19];

    // workspace layout (floats); total ~60.31M floats ≈ 242 MB
    float* ws   = (float*)d_ws;
    float* X    = ws;                       // 8,388,608
    float* XLN  = ws + 8388608L;            // 8,388,608
    float* REG  = ws + 16777216L;           // 33,554,432 (Q|KV|KVLN|AO aliased by MID)
    float* Qb   = REG;
    float* KVb  = REG + 8388608L;
    float* KVLN = REG + 16777216L;
    float* AO   = REG + 25165824L;
    float* MID  = REG;                      // [16384 x 2048] after attention done
    float* Gb   = ws + 50331648L;           // 524,288
    float* W1T  = ws + 50855936L;           // 9,437,184
    int*   MASKN = (int*)(ws + 60293120L);  // 16,384
    int*   FLAGS = (int*)(ws + 60309504L);

    float* out_x  = (float*)d_out;
    float* out_we = out_x + 8388608L;

    mask_detect_kernel<<<1, 256, 0, stream>>>((const unsigned char*)mraw, FLAGS);
    mask_norm_kernel<<<64, 256, 0, stream>>>((const unsigned char*)mraw, FLAGS, MASKN);
    embed_kernel<<<32768, 256, 0, stream>>>(src_seq, emb, X, out_we);

    for (int l = 0; l < 4; ++l) {
        ln_row_kernel<<<16384, 256, 0, stream>>>(X, XLN, ln1_g + l * 512, ln1_b + l * 512);
        gemm_nt_kernel<<<dim3(128, 4), 256, 0, stream>>>(
            XLN, 512, Wq + (long)l * 262144, 512, 0L, 1, 0,
            Qb, 512, 512, nullptr, nullptr, nullptr, 0);
        gemm_nt_kernel<<<dim3(128, 4), 256, 0, stream>>>(
            XLN, 512, Wkv + (long)l * 262144, 512, 0L, 1, 0,
            KVb, 512, 512, nullptr, nullptr, nullptr, 0);
        rope_kernel<<<16384, 256, 0, stream>>>(Qb, 0.125f);   // * DH^-0.5
        rope_kernel<<<16384, 256, 0, stream>>>(KVb, 1.0f);
        ln_head_kernel<<<32768, 256, 0, stream>>>(KVb, KVLN, lng + l * 64, lnb + l * 64);
        globalkv_kernel<<<2048, 256, 0, stream>>>(KVb, Wp + l * 64, gng + l * 64,
                                                  gnb + l * 64, MASKN, Gb);
        attn_kernel<<<dim3(16, 64), 256, 0, stream>>>(Qb, KVLN, Gb, lnb + l * 64, MASKN, AO);
        gemm_nt_kernel<<<dim3(128, 4), 256, 0, stream>>>(
            AO, 512, Wo + (long)l * 262144, 512, 0L, 1, 0,
            X, 512, 512, bo + l * 512, X, MASKN, 0);
        ln_row_kernel<<<16384, 256, 0, stream>>>(X, XLN, ln2_g + l * 512, ln2_b + l * 512);
        w1t_kernel<<<2048, 256, 0, stream>>>(w1 + (long)l * 9437184L, W1T);
        gemm_nt_kernel<<<dim3(128, 16), 256, 0, stream>>>(
            XLN, 512, W1T, 512, 1048576L, 9, -4,
            MID, 2048, 512, b1 + l * 2048, nullptr, nullptr, 1);
        gemm_nt_kernel<<<dim3(128, 4), 256, 0, stream>>>(
            MID, 2048, w2 + (long)l * 1048576L, 2048, 0L, 1, 0,
            X, 512, 2048, b2 + l * 512, X, MASKN, 0);
    }
    hipMemcpyAsync(out_x, X, 8388608L * sizeof(float), hipMemcpyDeviceToDevice, stream);
}

// Round 2
// 8196.614 us; speedup vs baseline: 2.4653x; 2.4653x over previous
//
#include <hip/hip_runtime.h>
#include <math.h>

// ---------------------------------------------------------------------------
// Long-short transformer encoder, MI355X. Round 2: all GEMMs on MFMA via
// bf16x3 split precision (C = Ah*Bh + Ah*Bl + Al*Bh, fp32 accumulate).
// ---------------------------------------------------------------------------

typedef unsigned short u16;
typedef __attribute__((ext_vector_type(8))) short short8;
typedef __attribute__((ext_vector_type(4))) float f32x4;

#define NEGF (-3.4028234663852886e38f)
#define SEQ    2048
#define DMODEL 512
#define PADR   2056   // padded rows per sequence (4 zero rows each side)

__device__ __forceinline__ u16 f2bf(float f) {
    unsigned u = __float_as_uint(f);
    u += 0x7fffu + ((u >> 16) & 1u);
    return (u16)(u >> 16);
}
__device__ __forceinline__ float bf2f(u16 h) {
    return __uint_as_float(((unsigned)h) << 16);
}

__device__ __forceinline__ void gload16(const void* g, void* l) {
    __builtin_amdgcn_global_load_lds(
        (const __attribute__((address_space(1))) unsigned int*)(g),
        (__attribute__((address_space(3))) unsigned int*)(unsigned long)(l),
        16, 0, 0);
}

// ---------------------------- mask normalization ---------------------------
__global__ __launch_bounds__(256) void mask_detect_kernel(
    const unsigned char* __restrict__ m, int* __restrict__ flags)
{
    __shared__ int sA, sB;
    const int tid = threadIdx.x;
    if (tid == 0) { sA = 0; sB = 0; }
    __syncthreads();
    int a = 0, b8 = 0;
    for (int i = tid; i < 16384; i += 256) {
        const unsigned char v = m[i];
        if (i & 3) a |= v;
        if ((i & 7) == 4) b8 |= v;
    }
    atomicOr(&sA, a);
    atomicOr(&sB, b8);
    __syncthreads();
    if (tid == 0) { flags[0] = sA; flags[1] = sB; }
}

__global__ __launch_bounds__(256) void mask_norm_kernel(
    const unsigned char* __restrict__ m, const int* __restrict__ flags,
    int* __restrict__ out)
{
    const int i = blockIdx.x * 256 + threadIdx.x;  // < 16384
    const int a = flags[0], b8 = flags[1];
    int v;
    if (a == 0)               v = b8 ? m[4L * i] : m[8L * i];   // int32 / int64
    else if ((a & ~1) == 0)   v = m[i];                         // bool bytes
    else                      v = (m[4L*i+1] | m[4L*i+2] | m[4L*i+3]) != 0; // f32
    out[i] = (v != 0) ? 1 : 0;
}

// --------------------------- embedding + sinusoid --------------------------
__global__ __launch_bounds__(256) void embed_kernel(
    const int* __restrict__ seq, const float* __restrict__ emb,
    float* __restrict__ X, float* __restrict__ we)
{
    const long idx = (long)blockIdx.x * 256 + threadIdx.x;  // < 8388608
    const int  d  = (int)(idx & 511);
    const long bn = idx >> 9;
    const int  n  = (int)(bn & (SEQ - 1));
    const int tok = seq[bn];
    const float e = emb[(long)tok * DMODEL + d];
    we[idx] = e;
    const float denom = (float)pow(10000.0, (double)(d & ~1) / 512.0);
    const float angle = (float)n / denom;
    const float sval  = (d & 1) ? cosf(angle) : sinf(angle);
    X[idx] = e + sval;
}

// ---------------------- zero the pad rows of APAD (once) -------------------
__global__ __launch_bounds__(256) void zero_pad_kernel(u16* __restrict__ APAD)
{
    const int i = blockIdx.x * 256 + threadIdx.x;  // < 65536
    const int s  = i >> 13;
    const int r8 = (i >> 10) & 7;
    const int c  = i & 1023;
    const int row = (r8 < 4) ? r8 : (PADR - 8 + r8);
    APAD[((long)s * PADR + row) * 1024 + c] = 0;
}

// ----------------- row LayerNorm -> bf16 hi/lo into padded A ---------------
__global__ __launch_bounds__(256) void ln_row_bf16_kernel(
    const float* __restrict__ X, u16* __restrict__ APAD,
    const float* __restrict__ g, const float* __restrict__ bb)
{
    const int row = blockIdx.x;
    const int tid = threadIdx.x;
    const float2 v = *(const float2*)&X[(long)row * DMODEL + tid * 2];
    float s  = v.x + v.y;
    float sq = v.x * v.x + v.y * v.y;
    #pragma unroll
    for (int o = 32; o > 0; o >>= 1) { s += __shfl_xor(s, o); sq += __shfl_xor(sq, o); }
    __shared__ float rs[4], rq[4];
    const int wv = tid >> 6, lane = tid & 63;
    if (lane == 0) { rs[wv] = s; rq[wv] = sq; }
    __syncthreads();
    s  = rs[0] + rs[1] + rs[2] + rs[3];
    sq = rq[0] + rq[1] + rq[2] + rq[3];
    const float mean = s * (1.f / 512.f);
    const float var  = sq * (1.f / 512.f) - mean * mean;
    const float inv  = rsqrtf(var + 1e-5f);
    const float2 gv = *(const float2*)&g[tid * 2];
    const float2 bv = *(const float2*)&bb[tid * 2];
    const float ox = (v.x - mean) * inv * gv.x + bv.x;
    const float oy = (v.y - mean) * inv * gv.y + bv.y;
    const long grow = (long)(row >> 11) * PADR + 4 + (row & 2047);
    u16* dst = APAD + grow * 1024;
    const int c = tid * 2;
    const u16 hx = f2bf(ox), hy = f2bf(oy);
    dst[c]     = hx;               dst[c + 1]       = hy;
    dst[512+c] = f2bf(ox - bf2f(hx)); dst[512+c+1] = f2bf(oy - bf2f(hy));
}

// ------------------------- head-wise LayerNorm (DH=64) ---------------------
__global__ __launch_bounds__(256) void ln_head_kernel(
    const float* __restrict__ X, float* __restrict__ Y,
    const float* __restrict__ g, const float* __restrict__ bb)
{
    const int grp  = blockIdx.x * 4 + (threadIdx.x >> 6);
    const int lane = threadIdx.x & 63;
    const long off = (long)grp * 64 + lane;
    const float x = X[off];
    float mean = x;
    #pragma unroll
    for (int o = 32; o > 0; o >>= 1) mean += __shfl_xor(mean, o);
    mean *= (1.f / 64.f);
    const float d = x - mean;
    float var = d * d;
    #pragma unroll
    for (int o = 32; o > 0; o >>= 1) var += __shfl_xor(var, o);
    var *= (1.f / 64.f);
    Y[off] = d * rsqrtf(var + 1e-5f) * g[lane] + bb[lane];
}

// ---------------------------------- rotary ---------------------------------
__global__ __launch_bounds__(256) void rope_kernel(float* __restrict__ T, float scale)
{
    const long idx = (long)blockIdx.x * 256 + threadIdx.x;  // < 4194304
    const int  i   = (int)(idx & 31);
    const long rem = idx >> 5;
    const int  h   = (int)(rem & 7);
    const long bn  = rem >> 3;
    const int  n   = (int)(bn & (SEQ - 1));
    const float inv = (float)pow(10000.0, -(double)i / 32.0);
    const float f = (float)n * inv;
    float s, c;
    sincosf(f, &s, &c);
    const long o = bn * DMODEL + (long)h * 64 + i;
    const float t0 = T[o], t1 = T[o + 32];
    T[o]      = (t0 * c - t1 * s) * scale;
    T[o + 32] = (t1 * c + t0 * s) * scale;
}

// --------------------- global KV summaries (Wp, softmax, LN) ---------------
__global__ __launch_bounds__(256) void globalkv_kernel(
    const float* __restrict__ KV, const float* __restrict__ Wp,
    const float* __restrict__ gng, const float* __restrict__ gnb,
    const int* __restrict__ maskn, float* __restrict__ G)
{
    const int tid  = threadIdx.x;
    const int lane = tid & 63;
    const int wv   = tid >> 6;
    const int grp  = blockIdx.x * 4 + wv;     // bh*128 + s, < 8192
    const int bh   = grp >> 7;
    const int sseg = grp & 127;
    const int b = bh >> 3, h = bh & 7;
    const float wp = Wp[lane];
    const float* base = KV + ((long)(b * SEQ + sseg * 16)) * DMODEL + h * 64 + lane;
    float kvv[16], p[16];
    #pragma unroll
    for (int i = 0; i < 16; ++i) kvv[i] = base[(long)i * DMODEL];
    #pragma unroll
    for (int i = 0; i < 16; ++i) {
        float t = kvv[i] * wp;
        #pragma unroll
        for (int o = 32; o > 0; o >>= 1) t += __shfl_xor(t, o);
        const int keep = maskn[b * SEQ + sseg * 16 + i];
        p[i] = keep ? t : NEGF;
    }
    float m = p[0];
    #pragma unroll
    for (int i = 1; i < 16; ++i) m = fmaxf(m, p[i]);
    float sum = 0.f;
    #pragma unroll
    for (int i = 0; i < 16; ++i) { p[i] = expf(p[i] - m); sum += p[i]; }
    const float inv = 1.f / sum;
    float gd = 0.f;
    #pragma unroll
    for (int i = 0; i < 16; ++i) gd = fmaf(p[i] * inv, kvv[i], gd);
    float mean = gd;
    #pragma unroll
    for (int o = 32; o > 0; o >>= 1) mean += __shfl_xor(mean, o);
    mean *= (1.f / 64.f);
    const float d = gd - mean;
    float var = d * d;
    #pragma unroll
    for (int o = 32; o > 0; o >>= 1) var += __shfl_xor(var, o);
    var *= (1.f / 64.f);
    G[(long)grp * 64 + lane] = d * rsqrtf(var + 1e-5f) * gng[lane] + gnb[lane];
}

// ----------------------- fused long-short attention ------------------------
// Output written pre-split as bf16 hi/lo into AOp [16384][1024].
__global__ __launch_bounds__(256) void attn_kernel(
    const float* __restrict__ Q, const float* __restrict__ KVLN,
    const float* __restrict__ G, const float* __restrict__ lnb,
    const int* __restrict__ maskn, u16* __restrict__ AOp)
{
    __shared__ float sk[384][65];
    __shared__ float qs[128][64];
    __shared__ __align__(16) float ps[4][384][4];
    __shared__ int lm[256];
    const int w  = blockIdx.x;   // 0..15
    const int bh = blockIdx.y;   // 0..63
    const int b = bh >> 3, h = bh & 7;
    const int tid = threadIdx.x;
    const int lane = tid & 63;
    const int wv = tid >> 6;

    for (int idx = tid; idx < 384 * 16; idx += 256) {
        const int slot = idx >> 4;
        const int dq = (idx & 15) << 2;
        float4 v;
        if (slot < 128) {
            v = *(const float4*)&G[((long)(bh * 128 + slot)) * 64 + dq];
        } else {
            const int kn = (w - 1) * 128 + (slot - 128);
            if (kn < 0) v = make_float4(lnb[dq], lnb[dq+1], lnb[dq+2], lnb[dq+3]);
            else v = *(const float4*)&KVLN[((long)(b * SEQ + kn)) * DMODEL + h * 64 + dq];
        }
        sk[slot][dq] = v.x; sk[slot][dq+1] = v.y; sk[slot][dq+2] = v.z; sk[slot][dq+3] = v.w;
    }
    for (int idx = tid; idx < 128 * 16; idx += 256) {
        const int r = idx >> 4;
        const int dq = (idx & 15) << 2;
        const float4 v = *(const float4*)&Q[((long)(b * SEQ + w * 128 + r)) * DMODEL + h * 64 + dq];
        qs[r][dq] = v.x; qs[r][dq+1] = v.y; qs[r][dq+2] = v.z; qs[r][dq+3] = v.w;
    }
    {
        const int kn = (w - 1) * 128 + tid;
        lm[tid & 255] = (kn >= 0 && tid < 256) ? maskn[b * SEQ + kn] : (tid < 256 ? 0 : lm[tid & 255]);
    }
    __syncthreads();

    for (int g4 = 0; g4 < 8; ++g4) {
        const int i0 = wv * 32 + g4 * 4;
        float s[4][6];
        #pragma unroll
        for (int r = 0; r < 4; ++r)
            #pragma unroll
            for (int t = 0; t < 6; ++t) s[r][t] = 0.f;
        #pragma unroll 4
        for (int k = 0; k < 64; ++k) {
            const float q0 = qs[i0 + 0][k];
            const float q1 = qs[i0 + 1][k];
            const float q2 = qs[i0 + 2][k];
            const float q3 = qs[i0 + 3][k];
            #pragma unroll
            for (int t = 0; t < 6; ++t) {
                const float kv = sk[t * 64 + lane][k];
                s[0][t] = fmaf(q0, kv, s[0][t]);
                s[1][t] = fmaf(q1, kv, s[1][t]);
                s[2][t] = fmaf(q2, kv, s[2][t]);
                s[3][t] = fmaf(q3, kv, s[3][t]);
            }
        }
        #pragma unroll
        for (int r = 0; r < 4; ++r) {
            const int i = i0 + r;
            const int n = w * 128 + i;
            #pragma unroll
            for (int t = 0; t < 6; ++t) {
                const int j = t * 64 + lane;
                bool ok;
                if (j < 128) ok = (n >= (j + 1) * 16 - 1);
                else {
                    const int jj = j - 128;
                    ok = (jj <= i + 128) && (lm[jj] != 0);
                }
                if (!ok) s[r][t] = NEGF;
            }
            float m = s[r][0];
            #pragma unroll
            for (int t = 1; t < 6; ++t) m = fmaxf(m, s[r][t]);
            #pragma unroll
            for (int o = 32; o > 0; o >>= 1) m = fmaxf(m, __shfl_xor(m, o));
            float e[6]; float sum = 0.f;
            #pragma unroll
            for (int t = 0; t < 6; ++t) { e[t] = expf(s[r][t] - m); sum += e[t]; }
            #pragma unroll
            for (int o = 32; o > 0; o >>= 1) sum += __shfl_xor(sum, o);
            const float inv = 1.f / sum;
            #pragma unroll
            for (int t = 0; t < 6; ++t) ps[wv][t * 64 + lane][r] = e[t] * inv;
        }
        __syncthreads();
        float o0 = 0.f, o1 = 0.f, o2 = 0.f, o3 = 0.f;
        #pragma unroll 4
        for (int j = 0; j < 384; ++j) {
            const float kv = sk[j][lane];
            const float4 p4 = *(const float4*)&ps[wv][j][0];
            o0 = fmaf(p4.x, kv, o0);
            o1 = fmaf(p4.y, kv, o1);
            o2 = fmaf(p4.z, kv, o2);
            o3 = fmaf(p4.w, kv, o3);
        }
        const long r0w = (long)(b * SEQ + w * 128 + i0);
        const int col = h * 64 + lane;
        const u16 h0 = f2bf(o0), h1 = f2bf(o1), h2 = f2bf(o2), h3 = f2bf(o3);
        AOp[(r0w    ) * 1024 + col] = h0; AOp[(r0w    ) * 1024 + 512 + col] = f2bf(o0 - bf2f(h0));
        AOp[(r0w + 1) * 1024 + col] = h1; AOp[(r0w + 1) * 1024 + 512 + col] = f2bf(o1 - bf2f(h1));
        AOp[(r0w + 2) * 1024 + col] = h2; AOp[(r0w + 2) * 1024 + 512 + col] = f2bf(o2 - bf2f(h2));
        AOp[(r0w + 3) * 1024 + col] = h3; AOp[(r0w + 3) * 1024 + 512 + col] = f2bf(o3 - bf2f(h3));
    }
}

// ----------------- weight fp32 [N][K] -> bf16 [N][K hi | K lo] -------------
__global__ __launch_bounds__(256) void cvt_pair_kernel(
    const float* __restrict__ src, u16* __restrict__ dst, int kshift)
{
    const long i = (long)blockIdx.x * 256 + threadIdx.x;
    const int K = 1 << kshift;
    const long row = i >> kshift;
    const int k = (int)(i & (K - 1));
    const float v = src[i];
    const u16 h = f2bf(v);
    u16* d = dst + (row << (kshift + 1));
    d[k] = h;
    d[K + k] = f2bf(v - bf2f(h));
}

// ------------- w1 [f][c][k] -> W1T [k][f][512 c-hi | 512 c-lo] -------------
__global__ __launch_bounds__(256) void w1t_bf16_kernel(
    const float* __restrict__ w1, u16* __restrict__ W1T)
{
    __shared__ float ld[4608];
    const int f = blockIdx.x;      // 0..2047
    const float* src = w1 + (long)f * 4608;
    for (int i = threadIdx.x; i < 4608; i += 256) ld[i] = src[i];
    __syncthreads();
    for (int k = 0; k < 9; ++k)
        for (int c = threadIdx.x; c < 512; c += 256) {
            const float v = ld[c * 9 + k];
            const u16 h = f2bf(v);
            u16* d = W1T + ((long)k * 2048 + f) * 1024;
            d[c] = h;
            d[512 + c] = f2bf(v - bf2f(h));
        }
}

// ----------------------------- MFMA GEMM (bf16x3) --------------------------
// C[r][c] = sum over shifts sh, terms {(Ah,Bh),(Ah,Bl),(Al,Bh)}, k:
//           A[rowmap(r)+sh][k] * B_sh[c][k]
// rowmap(r) = (r>>11)*seqStride + padOff + (r&2047): padded-seq A layouts.
// Epilogue: +bias, GELU, (+resid, mask-zero -> fp32 C) or bf16 hi/lo pair out.
__global__ __launch_bounds__(256) void gemm_mfma_kernel(
    const u16* __restrict__ Ah, const u16* __restrict__ Al, int ldA,
    int seqStride, int padOff, int shift0, int nShift,
    const u16* __restrict__ Bh, const u16* __restrict__ Bl, int ldB, long bShiftEl,
    int K,
    float* __restrict__ C, int ldc,
    u16* __restrict__ OutH, u16* __restrict__ OutL, int ldo,
    const float* __restrict__ bias, const float* __restrict__ resid,
    const int* __restrict__ maskrow, int gelu_flag)
{
    __shared__ __align__(16) u16 Alds[128][64];
    __shared__ __align__(16) u16 Blds[128][64];
    const int tid  = threadIdx.x;
    const int lane = tid & 63;
    const int wv   = tid >> 6;
    const int wr   = (wv >> 1) * 64;
    const int wc   = (wv & 1) * 64;
    const int row0 = blockIdx.x * 128;
    const int col0 = blockIdx.y * 128;
    const long rowA0 = (long)(row0 >> 11) * seqStride + padOff + (row0 & 2047);
    const int sr = tid >> 3;          // staging row within 32-row slab
    const int sc = (tid & 7) * 8;     // staging col (elems)
    char* const aldsB = (char*)(&Alds[0][0]) + wv * 1024;
    char* const bldsB = (char*)(&Blds[0][0]) + wv * 1024;

    f32x4 acc[4][4];
    #pragma unroll
    for (int m = 0; m < 4; ++m)
        #pragma unroll
        for (int n = 0; n < 4; ++n)
            acc[m][n] = (f32x4){0.f, 0.f, 0.f, 0.f};

    const int rr = lane & 15;
    const int kb = (lane >> 4) * 8;

    for (int sh = 0; sh < nShift; ++sh) {
        const int shv = shift0 + sh;
        #pragma unroll 1
        for (int term = 0; term < 3; ++term) {
            const u16* Ab = (term == 2) ? Al : Ah;
            const u16* Bb = ((term == 1) ? Bl : Bh) + (long)sh * bShiftEl;
            const u16* Ap = Ab + (rowA0 + shv + sr) * (long)ldA + sc;
            const u16* Bp = Bb + (long)(col0 + sr) * ldB + sc;
            #pragma unroll 1
            for (int k0 = 0; k0 < K; k0 += 64) {
                #pragma unroll
                for (int it = 0; it < 4; ++it) {
                    gload16(Ap + (long)(it * 32) * ldA + k0, aldsB + it * 4096);
                    gload16(Bp + (long)(it * 32) * ldB + k0, bldsB + it * 4096);
                }
                __syncthreads();   // drains vmcnt: LDS tiles complete
                #pragma unroll
                for (int ks = 0; ks < 2; ++ks) {
                    short8 af[4], bfr[4];
                    #pragma unroll
                    for (int m = 0; m < 4; ++m)
                        af[m] = *(const short8*)&Alds[wr + m * 16 + rr][ks * 32 + kb];
                    #pragma unroll
                    for (int n = 0; n < 4; ++n)
                        bfr[n] = *(const short8*)&Blds[wc + n * 16 + rr][ks * 32 + kb];
                    #pragma unroll
                    for (int m = 0; m < 4; ++m)
                        #pragma unroll
                        for (int n = 0; n < 4; ++n)
                            acc[m][n] = __builtin_amdgcn_mfma_f32_16x16x32_bf16(
                                af[m], bfr[n], acc[m][n], 0, 0, 0);
                }
                __syncthreads();   // all reads done before next stage
            }
        }
    }

    // epilogue: C/D layout col = lane&15, row = (lane>>4)*4 + reg
    const int er = (lane >> 4) * 4;
    const int ec = lane & 15;
    #pragma unroll
    for (int m = 0; m < 4; ++m) {
        #pragma unroll
        for (int q = 0; q < 4; ++q) {
            const int r = row0 + wr + m * 16 + er + q;
            const int mz = maskrow ? maskrow[r] : 0;
            #pragma unroll
            for (int n = 0; n < 4; ++n) {
                const int c = col0 + wc + n * 16 + ec;
                float v = acc[m][n][q];
                if (bias) v += bias[c];
                if (gelu_flag) v = 0.5f * v * (1.f + erff(v * 0.70710678118654752f));
                if (OutH) {
                    const u16 h = f2bf(v);
                    OutH[(long)r * ldo + c] = h;
                    OutL[(long)r * ldo + c] = f2bf(v - bf2f(h));
                } else {
                    if (resid) v += resid[(long)r * ldc + c];
                    if (mz) v = 0.f;
                    C[(long)r * ldc + c] = v;
                }
            }
        }
    }
}

// --------------------------------- launcher --------------------------------
extern "C" void kernel_launch(void* const* d_in, const int* in_sizes, int n_in,
                              void* d_out, int out_size, void* d_ws, size_t ws_size,
                              hipStream_t stream)
{
    (void)in_sizes; (void)n_in; (void)out_size; (void)ws_size;
    const int*   src_seq = (const int*)d_in[0];
    const void*  mraw    = d_in[1];
    const float* emb     = (const float*)d_in[2];
    const float* ln1_g   = (const float*)d_in[3];
    const float* ln1_b   = (const float*)d_in[4];
    const float* Wq      = (const float*)d_in[5];
    const float* Wkv     = (const float*)d_in[6];
    const float* Wp      = (const float*)d_in[7];
    const float* lng     = (const float*)d_in[8];
    const float* lnb     = (const float*)d_in[9];
    const float* gng     = (const float*)d_in[10];
    const float* gnb     = (const float*)d_in[11];
    const float* Wo      = (const float*)d_in[12];
    const float* bo      = (const float*)d_in[13];
    const float* ln2_g   = (const float*)d_in[14];
    const float* ln2_b   = (const float*)d_in[15];
    const float* w1      = (const float*)d_in[16];
    const float* b1      = (const float*)d_in[17];
    const float* w2      = (const float*)d_in[18];
    const float* b2      = (const float*)d_in[19];

    // X lives in d_out (fully rewritten each launch); we = second output.
    float* X      = (float*)d_out;
    float* out_we = X + 8388608L;

    // workspace layout (byte offsets), total ~215.2 MB
    char* wsb = (char*)d_ws;
    u16*   APAD = (u16*)wsb;                                   // 33,685,504 B
    float* Qb   = (float*)(wsb + 33685504L);                   // 33,554,432
    float* KVb  = (float*)(wsb + 33685504L + 33554432L);       // 33,554,432
    float* KVLN = (float*)(wsb + 33685504L + 2*33554432L);     // 33,554,432
    u16*   AOp  = (u16*)  (wsb + 33685504L + 3*33554432L);     // 33,554,432
    u16*   MIDh = (u16*)(wsb + 33685504L);                     // alias Qb.. (67,108,864)
    u16*   MIDl = MIDh + (long)16384 * 2048;                   // (67,108,864)
    float* Gb   = (float*)(wsb + 167903232L);                  // 2,097,152
    u16*   Wqp  = (u16*)(wsb + 170000384L);                    // 1,048,576
    u16*   Wkvp = (u16*)(wsb + 171048960L);                    // 1,048,576
    u16*   Wop  = (u16*)(wsb + 172097536L);                    // 1,048,576
    u16*   w2p  = (u16*)(wsb + 173146112L);                    // 4,194,304
    u16*   W1Tp = (u16*)(wsb + 177340416L);                    // 37,748,736
    int*   MASKN = (int*)(wsb + 215089152L);                   // 65,536
    int*   FLAGS = (int*)(wsb + 215154688L);

    mask_detect_kernel<<<1, 256, 0, stream>>>((const unsigned char*)mraw, FLAGS);
    mask_norm_kernel<<<64, 256, 0, stream>>>((const unsigned char*)mraw, FLAGS, MASKN);
    embed_kernel<<<32768, 256, 0, stream>>>(src_seq, emb, X, out_we);
    zero_pad_kernel<<<256, 256, 0, stream>>>(APAD);

    for (int l = 0; l < 4; ++l) {
        // per-layer weight splits
        cvt_pair_kernel<<<1024, 256, 0, stream>>>(Wq  + (long)l *  262144L, Wqp,  9);
        cvt_pair_kernel<<<1024, 256, 0, stream>>>(Wkv + (long)l *  262144L, Wkvp, 9);
        cvt_pair_kernel<<<1024, 256, 0, stream>>>(Wo  + (long)l *  262144L, Wop,  9);
        cvt_pair_kernel<<<4096, 256, 0, stream>>>(w2  + (long)l * 1048576L, w2p, 11);
        w1t_bf16_kernel<<<2048, 256, 0, stream>>>(w1 + (long)l * 9437184L, W1Tp);

        ln_row_bf16_kernel<<<16384, 256, 0, stream>>>(X, APAD, ln1_g + l*512, ln1_b + l*512);
        gemm_mfma_kernel<<<dim3(128, 4), 256, 0, stream>>>(
            APAD, APAD + 512, 1024, PADR, 4, 0, 1,
            Wqp, Wqp + 512, 1024, 0L, 512,
            Qb, 512, nullptr, nullptr, 0, nullptr, nullptr, nullptr, 0);
        gemm_mfma_kernel<<<dim3(128, 4), 256, 0, stream>>>(
            APAD, APAD + 512, 1024, PADR, 4, 0, 1,
            Wkvp, Wkvp + 512, 1024, 0L, 512,
            KVb, 512, nullptr, nullptr, 0, nullptr, nullptr, nullptr, 0);
        rope_kernel<<<16384, 256, 0, stream>>>(Qb, 0.125f);
        rope_kernel<<<16384, 256, 0, stream>>>(KVb, 1.0f);
        ln_head_kernel<<<32768, 256, 0, stream>>>(KVb, KVLN, lng + l*64, lnb + l*64);
        globalkv_kernel<<<2048, 256, 0, stream>>>(KVb, Wp + l*64, gng + l*64,
                                                  gnb + l*64, MASKN, Gb);
        attn_kernel<<<dim3(16, 64), 256, 0, stream>>>(Qb, KVLN, Gb, lnb + l*64, MASKN, AOp);
        gemm_mfma_kernel<<<dim3(128, 4), 256, 0, stream>>>(
            AOp, AOp + 512, 1024, SEQ, 0, 0, 1,
            Wop, Wop + 512, 1024, 0L, 512,
            X, 512, nullptr, nullptr, 0, bo + l*512, X, MASKN, 0);
        ln_row_bf16_kernel<<<16384, 256, 0, stream>>>(X, APAD, ln2_g + l*512, ln2_b + l*512);
        gemm_mfma_kernel<<<dim3(128, 16), 256, 0, stream>>>(
            APAD, APAD + 512, 1024, PADR, 4, -4, 9,
            W1Tp, W1Tp + 512, 1024, 2048L * 1024L, 512,
            nullptr, 0, MIDh, MIDl, 2048, b1 + l*2048, nullptr, nullptr, 1);
        gemm_mfma_kernel<<<dim3(128, 4), 256, 0, stream>>>(
            MIDh, MIDl, 2048, SEQ, 0, 0, 1,
            w2p, w2p + 2048, 4096, 0L, 2048,
            X, 512, nullptr, nullptr, 0, b2 + l*512, X, MASKN, 0);
    }
}

// Round 7
// 6034.933 us; speedup vs baseline: 3.3483x; 1.3582x over previous
//
#include <hip/hip_runtime.h>
#include <math.h>

// ---------------------------------------------------------------------------
// Long-short transformer encoder, MI355X. Round 3 design (fifth submission;
// r3-r6 benches never ran due to GPU acquisition timeouts):
//  - GEMM: 4-tile (Ah,Al,Bh,Bl) single-stage BK=32, 48 MFMA per barrier-pair
//  - attention: 8-wave block, vectorized LDS, bf16-packed P, group-split PV
//  - exp2f instead of double pow; packed bf16 stores
// ---------------------------------------------------------------------------

typedef unsigned short u16;
typedef __attribute__((ext_vector_type(8))) short short8;
typedef __attribute__((ext_vector_type(4))) float f32x4;

#define NEGF (-3.4028234663852886e38f)
#define SEQ    2048
#define DMODEL 512
#define PADR   2056   // padded rows per sequence (4 zero rows each side)
#define LOG2_10K 13.287712379549449f

__device__ __forceinline__ u16 f2bf(float f) {
    unsigned u = __float_as_uint(f);
    u += 0x7fffu + ((u >> 16) & 1u);
    return (u16)(u >> 16);
}
__device__ __forceinline__ float bf2f(u16 h) {
    return __uint_as_float(((unsigned)h) << 16);
}

__device__ __forceinline__ void gload16(const void* g, void* l) {
    __builtin_amdgcn_global_load_lds(
        (const __attribute__((address_space(1))) unsigned int*)(g),
        (__attribute__((address_space(3))) unsigned int*)(unsigned long)(l),
        16, 0, 0);
}

// ---------------------------- mask normalization ---------------------------
__global__ __launch_bounds__(256) void mask_detect_kernel(
    const unsigned char* __restrict__ m, int* __restrict__ flags)
{
    __shared__ int sA, sB;
    const int tid = threadIdx.x;
    if (tid == 0) { sA = 0; sB = 0; }
    __syncthreads();
    int a = 0, b8 = 0;
    for (int i = tid; i < 16384; i += 256) {
        const unsigned char v = m[i];
        if (i & 3) a |= v;
        if ((i & 7) == 4) b8 |= v;
    }
    atomicOr(&sA, a);
    atomicOr(&sB, b8);
    __syncthreads();
    if (tid == 0) { flags[0] = sA; flags[1] = sB; }
}

__global__ __launch_bounds__(256) void mask_norm_kernel(
    const unsigned char* __restrict__ m, const int* __restrict__ flags,
    int* __restrict__ out)
{
    const int i = blockIdx.x * 256 + threadIdx.x;  // < 16384
    const int a = flags[0], b8 = flags[1];
    int v;
    if (a == 0)               v = b8 ? m[4L * i] : m[8L * i];   // int32 / int64
    else if ((a & ~1) == 0)   v = m[i];                         // bool bytes
    else                      v = (m[4L*i+1] | m[4L*i+2] | m[4L*i+3]) != 0; // f32
    out[i] = (v != 0) ? 1 : 0;
}

// --------------------------- embedding + sinusoid --------------------------
__global__ __launch_bounds__(256) void embed_kernel(
    const int* __restrict__ seq, const float* __restrict__ emb,
    float* __restrict__ X, float* __restrict__ we)
{
    const long idx = (long)blockIdx.x * 256 + threadIdx.x;  // < 8388608
    const int  d  = (int)(idx & 511);
    const long bn = idx >> 9;
    const int  n  = (int)(bn & (SEQ - 1));
    const int tok = seq[bn];
    const float e = emb[(long)tok * DMODEL + d];
    we[idx] = e;
    const float angle = (float)n * exp2f(-(float)(d & ~1) * (LOG2_10K / 512.f));
    const float sval  = (d & 1) ? cosf(angle) : sinf(angle);
    X[idx] = e + sval;
}

// ---------------------- zero the pad rows of APAD (once) -------------------
__global__ __launch_bounds__(256) void zero_pad_kernel(u16* __restrict__ APAD)
{
    const int i = blockIdx.x * 256 + threadIdx.x;  // < 65536
    const int s  = i >> 13;
    const int r8 = (i >> 10) & 7;
    const int c  = i & 1023;
    const int row = (r8 < 4) ? r8 : (PADR - 8 + r8);
    APAD[((long)s * PADR + row) * 1024 + c] = 0;
}

// ----------------- row LayerNorm -> bf16 hi/lo into padded A ---------------
__global__ __launch_bounds__(256) void ln_row_bf16_kernel(
    const float* __restrict__ X, u16* __restrict__ APAD,
    const float* __restrict__ g, const float* __restrict__ bb)
{
    const int row = blockIdx.x;
    const int tid = threadIdx.x;
    const float2 v = *(const float2*)&X[(long)row * DMODEL + tid * 2];
    float s  = v.x + v.y;
    float sq = v.x * v.x + v.y * v.y;
    #pragma unroll
    for (int o = 32; o > 0; o >>= 1) { s += __shfl_xor(s, o); sq += __shfl_xor(sq, o); }
    __shared__ float rs[4], rq[4];
    const int wv = tid >> 6, lane = tid & 63;
    if (lane == 0) { rs[wv] = s; rq[wv] = sq; }
    __syncthreads();
    s  = rs[0] + rs[1] + rs[2] + rs[3];
    sq = rq[0] + rq[1] + rq[2] + rq[3];
    const float mean = s * (1.f / 512.f);
    const float var  = sq * (1.f / 512.f) - mean * mean;
    const float inv  = rsqrtf(var + 1e-5f);
    const float2 gv = *(const float2*)&g[tid * 2];
    const float2 bv = *(const float2*)&bb[tid * 2];
    const float ox = (v.x - mean) * inv * gv.x + bv.x;
    const float oy = (v.y - mean) * inv * gv.y + bv.y;
    const long grow = (long)(row >> 11) * PADR + 4 + (row & 2047);
    unsigned* dst = (unsigned*)(APAD + grow * 1024);
    const u16 hx = f2bf(ox), hy = f2bf(oy);
    const u16 lx = f2bf(ox - bf2f(hx)), ly = f2bf(oy - bf2f(hy));
    dst[tid]       = (unsigned)hx | ((unsigned)hy << 16);
    dst[256 + tid] = (unsigned)lx | ((unsigned)ly << 16);
}

// ------------------------- head-wise LayerNorm (DH=64) ---------------------
__global__ __launch_bounds__(256) void ln_head_kernel(
    const float* __restrict__ X, float* __restrict__ Y,
    const float* __restrict__ g, const float* __restrict__ bb)
{
    const int grp  = blockIdx.x * 4 + (threadIdx.x >> 6);
    const int lane = threadIdx.x & 63;
    const long off = (long)grp * 64 + lane;
    const float x = X[off];
    float mean = x;
    #pragma unroll
    for (int o = 32; o > 0; o >>= 1) mean += __shfl_xor(mean, o);
    mean *= (1.f / 64.f);
    const float d = x - mean;
    float var = d * d;
    #pragma unroll
    for (int o = 32; o > 0; o >>= 1) var += __shfl_xor(var, o);
    var *= (1.f / 64.f);
    Y[off] = d * rsqrtf(var + 1e-5f) * g[lane] + bb[lane];
}

// ---------------------------------- rotary ---------------------------------
__global__ __launch_bounds__(256) void rope_kernel(float* __restrict__ T, float scale)
{
    const long idx = (long)blockIdx.x * 256 + threadIdx.x;  // < 1048576
    const int  i4  = (int)(idx & 7);
    const long rem = idx >> 3;
    const int  h   = (int)(rem & 7);
    const long bn  = rem >> 3;
    const int  n   = (int)(bn & (SEQ - 1));
    const int  i   = i4 * 4;
    const long o = bn * DMODEL + (long)h * 64 + i;
    float4 a = *(float4*)&T[o];
    float4 b = *(float4*)&T[o + 32];
    float sv[4], cv[4];
    #pragma unroll
    for (int q = 0; q < 4; ++q) {
        const float f = (float)n * exp2f(-(float)(i + q) * (LOG2_10K / 32.f));
        sincosf(f, &sv[q], &cv[q]);
    }
    float4 oa, ob;
    oa.x = (a.x * cv[0] - b.x * sv[0]) * scale;
    oa.y = (a.y * cv[1] - b.y * sv[1]) * scale;
    oa.z = (a.z * cv[2] - b.z * sv[2]) * scale;
    oa.w = (a.w * cv[3] - b.w * sv[3]) * scale;
    ob.x = (b.x * cv[0] + a.x * sv[0]) * scale;
    ob.y = (b.y * cv[1] + a.y * sv[1]) * scale;
    ob.z = (b.z * cv[2] + a.z * sv[2]) * scale;
    ob.w = (b.w * cv[3] + a.w * sv[3]) * scale;
    *(float4*)&T[o]      = oa;
    *(float4*)&T[o + 32] = ob;
}

// --------------------- global KV summaries (Wp, softmax, LN) ---------------
__global__ __launch_bounds__(256) void globalkv_kernel(
    const float* __restrict__ KV, const float* __restrict__ Wp,
    const float* __restrict__ gng, const float* __restrict__ gnb,
    const int* __restrict__ maskn, float* __restrict__ G)
{
    const int tid  = threadIdx.x;
    const int lane = tid & 63;
    const int wv   = tid >> 6;
    const int grp  = blockIdx.x * 4 + wv;     // bh*128 + s, < 8192
    const int bh   = grp >> 7;
    const int sseg = grp & 127;
    const int b = bh >> 3, h = bh & 7;
    const float wp = Wp[lane];
    const float* base = KV + ((long)(b * SEQ + sseg * 16)) * DMODEL + h * 64 + lane;
    float kvv[16], p[16];
    #pragma unroll
    for (int i = 0; i < 16; ++i) kvv[i] = base[(long)i * DMODEL];
    #pragma unroll
    for (int i = 0; i < 16; ++i) {
        float t = kvv[i] * wp;
        #pragma unroll
        for (int o = 32; o > 0; o >>= 1) t += __shfl_xor(t, o);
        const int keep = maskn[b * SEQ + sseg * 16 + i];
        p[i] = keep ? t : NEGF;
    }
    float m = p[0];
    #pragma unroll
    for (int i = 1; i < 16; ++i) m = fmaxf(m, p[i]);
    float sum = 0.f;
    #pragma unroll
    for (int i = 0; i < 16; ++i) { p[i] = expf(p[i] - m); sum += p[i]; }
    const float inv = 1.f / sum;
    float gd = 0.f;
    #pragma unroll
    for (int i = 0; i < 16; ++i) gd = fmaf(p[i] * inv, kvv[i], gd);
    float mean = gd;
    #pragma unroll
    for (int o = 32; o > 0; o >>= 1) mean += __shfl_xor(mean, o);
    mean *= (1.f / 64.f);
    const float d = gd - mean;
    float var = d * d;
    #pragma unroll
    for (int o = 32; o > 0; o >>= 1) var += __shfl_xor(var, o);
    var *= (1.f / 64.f);
    G[(long)grp * 64 + lane] = d * rsqrtf(var + 1e-5f) * gng[lane] + gnb[lane];
}

// ----------------------- fused long-short attention ------------------------
// 512 threads = 8 waves; wave wv owns rows wv*16 .. wv*16+15 (4 passes of 4).
// sk stride 68 -> 16B-aligned float4 LDS reads, uniform bank coverage.
// P packed bf16 (4 rows per 8B). PV: 4 lane-groups x 96 keys, 4 d per lane,
// cross-group shfl reduce. Output bf16 hi/lo pair.
__global__ __launch_bounds__(512) void attn_kernel(
    const float* __restrict__ Q, const float* __restrict__ KVLN,
    const float* __restrict__ G, const float* __restrict__ lnb,
    const int* __restrict__ maskn, u16* __restrict__ AOp)
{
    __shared__ float sk[384][68];
    __shared__ float qs[128][64];
    __shared__ uint2 psp[8][384];
    __shared__ int lm[256];
    const int w  = blockIdx.x;   // 0..15
    const int bh = blockIdx.y;   // 0..63
    const int b = bh >> 3, h = bh & 7;
    const int tid = threadIdx.x;
    const int lane = tid & 63;
    const int wv = tid >> 6;

    for (int idx = tid; idx < 384 * 16; idx += 512) {
        const int slot = idx >> 4;
        const int dq = (idx & 15) << 2;
        float4 v;
        if (slot < 128) {
            v = *(const float4*)&G[((long)(bh * 128 + slot)) * 64 + dq];
        } else {
            const int kn = (w - 1) * 128 + (slot - 128);
            if (kn < 0) v = make_float4(lnb[dq], lnb[dq+1], lnb[dq+2], lnb[dq+3]);
            else v = *(const float4*)&KVLN[((long)(b * SEQ + kn)) * DMODEL + h * 64 + dq];
        }
        *(float4*)&sk[slot][dq] = v;
    }
    for (int idx = tid; idx < 128 * 16; idx += 512) {
        const int r = idx >> 4;
        const int dq = (idx & 15) << 2;
        *(float4*)&qs[r][dq] =
            *(const float4*)&Q[((long)(b * SEQ + w * 128 + r)) * DMODEL + h * 64 + dq];
    }
    if (tid < 256) {
        const int kn = (w - 1) * 128 + tid;
        lm[tid] = (kn >= 0) ? maskn[b * SEQ + kn] : 0;
    }
    __syncthreads();

    for (int g4 = 0; g4 < 4; ++g4) {
        const int i0 = wv * 16 + g4 * 4;
        float s[4][6];
        #pragma unroll
        for (int r = 0; r < 4; ++r)
            #pragma unroll
            for (int t = 0; t < 6; ++t) s[r][t] = 0.f;

        for (int k4 = 0; k4 < 64; k4 += 4) {
            const float4 q0 = *(const float4*)&qs[i0 + 0][k4];
            const float4 q1 = *(const float4*)&qs[i0 + 1][k4];
            const float4 q2 = *(const float4*)&qs[i0 + 2][k4];
            const float4 q3 = *(const float4*)&qs[i0 + 3][k4];
            #pragma unroll
            for (int t = 0; t < 6; ++t) {
                const float4 kv = *(const float4*)&sk[t * 64 + lane][k4];
                s[0][t] = fmaf(q0.x,kv.x, fmaf(q0.y,kv.y, fmaf(q0.z,kv.z, fmaf(q0.w,kv.w, s[0][t]))));
                s[1][t] = fmaf(q1.x,kv.x, fmaf(q1.y,kv.y, fmaf(q1.z,kv.z, fmaf(q1.w,kv.w, s[1][t]))));
                s[2][t] = fmaf(q2.x,kv.x, fmaf(q2.y,kv.y, fmaf(q2.z,kv.z, fmaf(q2.w,kv.w, s[2][t]))));
                s[3][t] = fmaf(q3.x,kv.x, fmaf(q3.y,kv.y, fmaf(q3.z,kv.z, fmaf(q3.w,kv.w, s[3][t]))));
            }
        }

        float p_all[4][6];
        #pragma unroll
        for (int r = 0; r < 4; ++r) {
            const int i = i0 + r;
            const int n = w * 128 + i;
            #pragma unroll
            for (int t = 0; t < 6; ++t) {
                const int j = t * 64 + lane;
                bool ok;
                if (j < 128) ok = (n >= (j + 1) * 16 - 1);
                else {
                    const int jj = j - 128;
                    ok = (jj <= i + 128) && (lm[jj] != 0);
                }
                if (!ok) s[r][t] = NEGF;
            }
            float m = s[r][0];
            #pragma unroll
            for (int t = 1; t < 6; ++t) m = fmaxf(m, s[r][t]);
            #pragma unroll
            for (int o = 32; o > 0; o >>= 1) m = fmaxf(m, __shfl_xor(m, o));
            float sum = 0.f;
            #pragma unroll
            for (int t = 0; t < 6; ++t) {
                const float e = expf(s[r][t] - m);
                p_all[r][t] = e;
                sum += e;
            }
            #pragma unroll
            for (int o = 32; o > 0; o >>= 1) sum += __shfl_xor(sum, o);
            const float inv = 1.f / sum;
            #pragma unroll
            for (int t = 0; t < 6; ++t) p_all[r][t] *= inv;
        }
        #pragma unroll
        for (int t = 0; t < 6; ++t) {
            psp[wv][t * 64 + lane] = make_uint2(
                (unsigned)f2bf(p_all[0][t]) | ((unsigned)f2bf(p_all[1][t]) << 16),
                (unsigned)f2bf(p_all[2][t]) | ((unsigned)f2bf(p_all[3][t]) << 16));
        }
        // PV (per-wave psp: in-wave LDS ordering, no barrier needed)
        const int grp = lane >> 4;
        const int dl = (lane & 15) * 4;
        float oo[4][4];
        #pragma unroll
        for (int r = 0; r < 4; ++r)
            #pragma unroll
            for (int q = 0; q < 4; ++q) oo[r][q] = 0.f;
        #pragma unroll 4
        for (int jj = 0; jj < 96; ++jj) {
            const int j = grp * 96 + jj;
            const float4 vv = *(const float4*)&sk[j][dl];
            const uint2 pw = psp[wv][j];
            const float p0 = __uint_as_float(pw.x << 16);
            const float p1 = __uint_as_float(pw.x & 0xffff0000u);
            const float p2 = __uint_as_float(pw.y << 16);
            const float p3 = __uint_as_float(pw.y & 0xffff0000u);
            oo[0][0] = fmaf(p0, vv.x, oo[0][0]); oo[0][1] = fmaf(p0, vv.y, oo[0][1]);
            oo[0][2] = fmaf(p0, vv.z, oo[0][2]); oo[0][3] = fmaf(p0, vv.w, oo[0][3]);
            oo[1][0] = fmaf(p1, vv.x, oo[1][0]); oo[1][1] = fmaf(p1, vv.y, oo[1][1]);
            oo[1][2] = fmaf(p1, vv.z, oo[1][2]); oo[1][3] = fmaf(p1, vv.w, oo[1][3]);
            oo[2][0] = fmaf(p2, vv.x, oo[2][0]); oo[2][1] = fmaf(p2, vv.y, oo[2][1]);
            oo[2][2] = fmaf(p2, vv.z, oo[2][2]); oo[2][3] = fmaf(p2, vv.w, oo[2][3]);
            oo[3][0] = fmaf(p3, vv.x, oo[3][0]); oo[3][1] = fmaf(p3, vv.y, oo[3][1]);
            oo[3][2] = fmaf(p3, vv.z, oo[3][2]); oo[3][3] = fmaf(p3, vv.w, oo[3][3]);
        }
        #pragma unroll
        for (int r = 0; r < 4; ++r)
            #pragma unroll
            for (int q = 0; q < 4; ++q) {
                oo[r][q] += __shfl_xor(oo[r][q], 16);
                oo[r][q] += __shfl_xor(oo[r][q], 32);
            }
        const int ro = lane >> 4;
        const int dq = (lane & 15) * 4;
        float u[4];
        #pragma unroll
        for (int q = 0; q < 4; ++q)
            u[q] = (ro == 0) ? oo[0][q] : (ro == 1) ? oo[1][q] : (ro == 2) ? oo[2][q] : oo[3][q];
        const u16 h0 = f2bf(u[0]), h1 = f2bf(u[1]), h2 = f2bf(u[2]), h3 = f2bf(u[3]);
        const u16 l0 = f2bf(u[0] - bf2f(h0)), l1 = f2bf(u[1] - bf2f(h1));
        const u16 l2 = f2bf(u[2] - bf2f(h2)), l3 = f2bf(u[3] - bf2f(h3));
        u16* obase = AOp + ((long)(b * SEQ + w * 128 + i0 + ro)) * 1024 + h * 64 + dq;
        *(uint2*)obase = make_uint2((unsigned)h0 | ((unsigned)h1 << 16),
                                    (unsigned)h2 | ((unsigned)h3 << 16));
        *(uint2*)(obase + 512) = make_uint2((unsigned)l0 | ((unsigned)l1 << 16),
                                            (unsigned)l2 | ((unsigned)l3 << 16));
    }
}

// ----------------- weight fp32 [N][K] -> bf16 [N][K hi | K lo] -------------
__global__ __launch_bounds__(256) void cvt_pair_kernel(
    const float* __restrict__ src, u16* __restrict__ dst, int kshift)
{
    const long i = (long)blockIdx.x * 256 + threadIdx.x;
    const int K = 1 << kshift;
    const long row = i >> kshift;
    const int k = (int)(i & (K - 1));
    const float v = src[i];
    const u16 h = f2bf(v);
    u16* d = dst + (row << (kshift + 1));
    d[k] = h;
    d[K + k] = f2bf(v - bf2f(h));
}

// ------------- w1 [f][c][k] -> W1T [k][f][512 c-hi | 512 c-lo] -------------
__global__ __launch_bounds__(256) void w1t_bf16_kernel(
    const float* __restrict__ w1, u16* __restrict__ W1T)
{
    __shared__ float ld[4608];
    const int f = blockIdx.x;      // 0..2047
    const float* src = w1 + (long)f * 4608;
    for (int i = threadIdx.x; i < 4608; i += 256) ld[i] = src[i];
    __syncthreads();
    for (int k = 0; k < 9; ++k)
        for (int c = threadIdx.x; c < 512; c += 256) {
            const float v = ld[c * 9 + k];
            const u16 h = f2bf(v);
            u16* d = W1T + ((long)k * 2048 + f) * 1024;
            d[c] = h;
            d[512 + c] = f2bf(v - bf2f(h));
        }
}

// ----------------------------- MFMA GEMM (bf16x3) --------------------------
// 4 LDS tiles resident (Ah,Al,Bh,Bl; 128x32 each = 32KB total); per stage:
// 8 gload16/thread, one barrier-pair, 48 MFMA (AhBh + AlBh + AhBl).
__global__ __launch_bounds__(256) void gemm_mfma_kernel(
    const u16* __restrict__ Ah, const u16* __restrict__ Al, int ldA,
    int seqStride, int padOff, int shift0, int nShift,
    const u16* __restrict__ Bh, const u16* __restrict__ Bl, int ldB, long bShiftEl,
    int K,
    float* __restrict__ C, int ldc,
    u16* __restrict__ OutH, u16* __restrict__ OutL, int ldo,
    const float* __restrict__ bias, const float* __restrict__ resid,
    const int* __restrict__ maskrow, int gelu_flag)
{
    __shared__ __align__(16) u16 AhL[128][32];
    __shared__ __align__(16) u16 AlL[128][32];
    __shared__ __align__(16) u16 BhL[128][32];
    __shared__ __align__(16) u16 BlL[128][32];
    const int tid  = threadIdx.x;
    const int lane = tid & 63;
    const int wv   = tid >> 6;
    const int wr   = (wv >> 1) * 64;
    const int wc   = (wv & 1) * 64;
    const int row0 = blockIdx.x * 128;
    const int col0 = blockIdx.y * 128;
    const long rowA0 = (long)(row0 >> 11) * seqStride + padOff + (row0 & 2047);
    const int srow = wv * 32 + (lane >> 2);   // +it*16
    const int scol = (lane & 3) * 8;
    char* const ahB = (char*)(&AhL[0][0]) + wv * 2048;
    char* const alB = (char*)(&AlL[0][0]) + wv * 2048;
    char* const bhB = (char*)(&BhL[0][0]) + wv * 2048;
    char* const blB = (char*)(&BlL[0][0]) + wv * 2048;

    f32x4 acc[4][4];
    #pragma unroll
    for (int m = 0; m < 4; ++m)
        #pragma unroll
        for (int n = 0; n < 4; ++n)
            acc[m][n] = (f32x4){0.f, 0.f, 0.f, 0.f};

    const int rr = lane & 15;
    const int kb = (lane >> 4) * 8;

    for (int sh = 0; sh < nShift; ++sh) {
        const int shv = shift0 + sh;
        const u16* aH = Ah + (rowA0 + shv + srow) * (long)ldA + scol;
        const u16* aL = Al + (rowA0 + shv + srow) * (long)ldA + scol;
        const u16* bH = Bh + (long)sh * bShiftEl + (long)(col0 + srow) * ldB + scol;
        const u16* bL = Bl + (long)sh * bShiftEl + (long)(col0 + srow) * ldB + scol;
        for (int k0 = 0; k0 < K; k0 += 32) {
            #pragma unroll
            for (int it = 0; it < 2; ++it) {
                const long goA = (long)(it * 16) * ldA + k0;
                const long goB = (long)(it * 16) * ldB + k0;
                gload16(aH + goA, ahB + it * 1024);
                gload16(aL + goA, alB + it * 1024);
                gload16(bH + goB, bhB + it * 1024);
                gload16(bL + goB, blB + it * 1024);
            }
            __syncthreads();   // drains vmcnt: all four tiles resident
            short8 fa[4], fb[4], ft[4];
            #pragma unroll
            for (int m = 0; m < 4; ++m) fa[m] = *(const short8*)&AhL[wr + m * 16 + rr][kb];
            #pragma unroll
            for (int n = 0; n < 4; ++n) fb[n] = *(const short8*)&BhL[wc + n * 16 + rr][kb];
            #pragma unroll
            for (int m = 0; m < 4; ++m)
                #pragma unroll
                for (int n = 0; n < 4; ++n)
                    acc[m][n] = __builtin_amdgcn_mfma_f32_16x16x32_bf16(fa[m], fb[n], acc[m][n], 0, 0, 0);
            #pragma unroll
            for (int m = 0; m < 4; ++m) ft[m] = *(const short8*)&AlL[wr + m * 16 + rr][kb];
            #pragma unroll
            for (int m = 0; m < 4; ++m)
                #pragma unroll
                for (int n = 0; n < 4; ++n)
                    acc[m][n] = __builtin_amdgcn_mfma_f32_16x16x32_bf16(ft[m], fb[n], acc[m][n], 0, 0, 0);
            #pragma unroll
            for (int n = 0; n < 4; ++n) ft[n] = *(const short8*)&BlL[wc + n * 16 + rr][kb];
            #pragma unroll
            for (int m = 0; m < 4; ++m)
                #pragma unroll
                for (int n = 0; n < 4; ++n)
                    acc[m][n] = __builtin_amdgcn_mfma_f32_16x16x32_bf16(fa[m], ft[n], acc[m][n], 0, 0, 0);
            __syncthreads();   // reads done before next stage overwrites
        }
    }

    // epilogue: C/D layout col = lane&15, row = (lane>>4)*4 + reg
    const int er = (lane >> 4) * 4;
    const int ec = lane & 15;
    #pragma unroll
    for (int m = 0; m < 4; ++m) {
        #pragma unroll
        for (int q = 0; q < 4; ++q) {
            const int r = row0 + wr + m * 16 + er + q;
            const int mz = maskrow ? maskrow[r] : 0;
            #pragma unroll
            for (int n = 0; n < 4; ++n) {
                const int c = col0 + wc + n * 16 + ec;
                float v = acc[m][n][q];
                if (bias) v += bias[c];
                if (gelu_flag) v = 0.5f * v * (1.f + erff(v * 0.70710678118654752f));
                if (OutH) {
                    const u16 h = f2bf(v);
                    OutH[(long)r * ldo + c] = h;
                    OutL[(long)r * ldo + c] = f2bf(v - bf2f(h));
                } else {
                    if (resid) v += resid[(long)r * ldc + c];
                    if (mz) v = 0.f;
                    C[(long)r * ldc + c] = v;
                }
            }
        }
    }
}

// --------------------------------- launcher --------------------------------
extern "C" void kernel_launch(void* const* d_in, const int* in_sizes, int n_in,
                              void* d_out, int out_size, void* d_ws, size_t ws_size,
                              hipStream_t stream)
{
    (void)in_sizes; (void)n_in; (void)out_size; (void)ws_size;
    const int*   src_seq = (const int*)d_in[0];
    const void*  mraw    = d_in[1];
    const float* emb     = (const float*)d_in[2];
    const float* ln1_g   = (const float*)d_in[3];
    const float* ln1_b   = (const float*)d_in[4];
    const float* Wq      = (const float*)d_in[5];
    const float* Wkv     = (const float*)d_in[6];
    const float* Wp      = (const float*)d_in[7];
    const float* lng     = (const float*)d_in[8];
    const float* lnb     = (const float*)d_in[9];
    const float* gng     = (const float*)d_in[10];
    const float* gnb     = (const float*)d_in[11];
    const float* Wo      = (const float*)d_in[12];
    const float* bo      = (const float*)d_in[13];
    const float* ln2_g   = (const float*)d_in[14];
    const float* ln2_b   = (const float*)d_in[15];
    const float* w1      = (const float*)d_in[16];
    const float* b1      = (const float*)d_in[17];
    const float* w2      = (const float*)d_in[18];
    const float* b2      = (const float*)d_in[19];

    float* X      = (float*)d_out;
    float* out_we = X + 8388608L;

    char* wsb = (char*)d_ws;
    u16*   APAD = (u16*)wsb;                                   // 33,685,504 B
    float* Qb   = (float*)(wsb + 33685504L);                   // 33,554,432
    float* KVb  = (float*)(wsb + 33685504L + 33554432L);       // 33,554,432
    float* KVLN = (float*)(wsb + 33685504L + 2*33554432L);     // 33,554,432
    u16*   AOp  = (u16*)  (wsb + 33685504L + 3*33554432L);     // 33,554,432
    u16*   MIDh = (u16*)(wsb + 33685504L);                     // alias Qb..
    u16*   MIDl = MIDh + (long)16384 * 2048;
    float* Gb   = (float*)(wsb + 167903232L);                  // 2,097,152
    u16*   Wqp  = (u16*)(wsb + 170000384L);                    // 1,048,576
    u16*   Wkvp = (u16*)(wsb + 171048960L);                    // 1,048,576
    u16*   Wop  = (u16*)(wsb + 172097536L);                    // 1,048,576
    u16*   w2p  = (u16*)(wsb + 173146112L);                    // 4,194,304
    u16*   W1Tp = (u16*)(wsb + 177340416L);                    // 37,748,736
    int*   MASKN = (int*)(wsb + 215089152L);                   // 65,536
    int*   FLAGS = (int*)(wsb + 215154688L);

    mask_detect_kernel<<<1, 256, 0, stream>>>((const unsigned char*)mraw, FLAGS);
    mask_norm_kernel<<<64, 256, 0, stream>>>((const unsigned char*)mraw, FLAGS, MASKN);
    embed_kernel<<<32768, 256, 0, stream>>>(src_seq, emb, X, out_we);
    zero_pad_kernel<<<256, 256, 0, stream>>>(APAD);

    for (int l = 0; l < 4; ++l) {
        cvt_pair_kernel<<<1024, 256, 0, stream>>>(Wq  + (long)l *  262144L, Wqp,  9);
        cvt_pair_kernel<<<1024, 256, 0, stream>>>(Wkv + (long)l *  262144L, Wkvp, 9);
        cvt_pair_kernel<<<1024, 256, 0, stream>>>(Wo  + (long)l *  262144L, Wop,  9);
        cvt_pair_kernel<<<4096, 256, 0, stream>>>(w2  + (long)l * 1048576L, w2p, 11);
        w1t_bf16_kernel<<<2048, 256, 0, stream>>>(w1 + (long)l * 9437184L, W1Tp);

        ln_row_bf16_kernel<<<16384, 256, 0, stream>>>(X, APAD, ln1_g + l*512, ln1_b + l*512);
        gemm_mfma_kernel<<<dim3(128, 4), 256, 0, stream>>>(
            APAD, APAD + 512, 1024, PADR, 4, 0, 1,
            Wqp, Wqp + 512, 1024, 0L, 512,
            Qb, 512, nullptr, nullptr, 0, nullptr, nullptr, nullptr, 0);
        gemm_mfma_kernel<<<dim3(128, 4), 256, 0, stream>>>(
            APAD, APAD + 512, 1024, PADR, 4, 0, 1,
            Wkvp, Wkvp + 512, 1024, 0L, 512,
            KVb, 512, nullptr, nullptr, 0, nullptr, nullptr, nullptr, 0);
        rope_kernel<<<4096, 256, 0, stream>>>(Qb, 0.125f);
        rope_kernel<<<4096, 256, 0, stream>>>(KVb, 1.0f);
        ln_head_kernel<<<32768, 256, 0, stream>>>(KVb, KVLN, lng + l*64, lnb + l*64);
        globalkv_kernel<<<2048, 256, 0, stream>>>(KVb, Wp + l*64, gng + l*64,
                                                  gnb + l*64, MASKN, Gb);
        attn_kernel<<<dim3(16, 64), 512, 0, stream>>>(Qb, KVLN, Gb, lnb + l*64, MASKN, AOp);
        gemm_mfma_kernel<<<dim3(128, 4), 256, 0, stream>>>(
            AOp, AOp + 512, 1024, SEQ, 0, 0, 1,
            Wop, Wop + 512, 1024, 0L, 512,
            X, 512, nullptr, nullptr, 0, bo + l*512, X, MASKN, 0);
        ln_row_bf16_kernel<<<16384, 256, 0, stream>>>(X, APAD, ln2_g + l*512, ln2_b + l*512);
        gemm_mfma_kernel<<<dim3(128, 16), 256, 0, stream>>>(
            APAD, APAD + 512, 1024, PADR, 4, -4, 9,
            W1Tp, W1Tp + 512, 1024, 2048L * 1024L, 512,
            nullptr, 0, MIDh, MIDl, 2048, b1 + l*2048, nullptr, nullptr, 1);
        gemm_mfma_kernel<<<dim3(128, 4), 256, 0, stream>>>(
            MIDh, MIDl, 2048, SEQ, 0, 0, 1,
            w2p, w2p + 2048, 4096, 0L, 2048,
            X, 512, nullptr, nullptr, 0, b2 + l*512, X, MASKN, 0);
    }
}